// Round 4
// baseline (269.919 us; speedup 1.0000x reference)
//
#include <hip/hip_runtime.h>
#include <hip/hip_bf16.h>
#include <cstdint>

typedef __bf16 bf16_t;
typedef __bf16 bf16x8 __attribute__((ext_vector_type(8)));
typedef float  f32x4  __attribute__((ext_vector_type(4)));

#define MFMA16(a, b, c) __builtin_amdgcn_mfma_f32_16x16x32_bf16((a), (b), (c), 0, 0, 0)

constexpr int BB = 8, CC = 384, NHH = 6, TT = 1024;

union U8 { uint4 u; bf16_t h[8]; };
union U2 { unsigned int u; bf16_t h[2]; };

// ---------------------------------------------------------------------------
// K0: normalize all inputs to canonical bf16 in ws.
// Inputs are fp32 (R1's NaN proved a bf16 read of them poisons); the probe is
// kept for robustness: gamma==ones -> first u16 is 0x3F80 iff buffer is bf16.
// ---------------------------------------------------------------------------
struct CastArgs {
    const void* src[9];
    bf16_t*     dst[9];
    int         n[9];
};

__global__ __launch_bounds__(256) void cast_kernel(CastArgs a)
{
    const bool isbf = (((const unsigned short*)a.src[5])[0] == 0x3F80u);
    const int ai = blockIdx.y;
    const int n  = a.n[ai];
    bf16_t* dst  = a.dst[ai];
    const int t0     = (blockIdx.x * 256 + threadIdx.x) * 8;
    const int stride = gridDim.x * 256 * 8;
    if (isbf) {
        const bf16_t* s = (const bf16_t*)a.src[ai];
        for (int idx = t0; idx < n; idx += stride) {
            if (idx + 8 <= n) {
                *(uint4*)(dst + idx) = *(const uint4*)(s + idx);
            } else {
                for (int j = 0; idx + j < n; ++j) dst[idx + j] = s[idx + j];
            }
        }
    } else {
        const float* s = (const float*)a.src[ai];
        for (int idx = t0; idx < n; idx += stride) {
            if (idx + 8 <= n) {
                f32x4 v0 = *(const f32x4*)(s + idx);
                f32x4 v1 = *(const f32x4*)(s + idx + 4);
                U8 o;
                #pragma unroll
                for (int j = 0; j < 4; ++j) { o.h[j] = (bf16_t)v0[j]; o.h[4 + j] = (bf16_t)v1[j]; }
                *(uint4*)(dst + idx) = o.u;
            } else {
                for (int j = 0; idx + j < n; ++j) dst[idx + j] = (bf16_t)s[idx + j];
            }
        }
    }
}

// ---------------------------------------------------------------------------
// K1: QKV projection.  out[o,t] = sum_c W[o,c] * x[b,c,t]
// A = x^T (m=t, staged transposed in LDS), B = W rows (n=o, contiguous K).
// Writes qT[b][t][o], kT[b][t][o] (t-major -> contiguous-K frags later), vm[b][o][t].
// ---------------------------------------------------------------------------
__global__ __launch_bounds__(256) void qkv_kernel(
    const bf16_t* __restrict__ x,
    const bf16_t* __restrict__ Wq,
    const bf16_t* __restrict__ Wk,
    const bf16_t* __restrict__ Wv,
    bf16_t* __restrict__ qT,
    bf16_t* __restrict__ kT,
    bf16_t* __restrict__ vm)
{
    const int og = blockIdx.x;        // 0,1:q  2,3:k  4,5:v
    const int tt = blockIdx.y;        // 0..15
    const int b  = blockIdx.z;
    const int t0 = tt * 64;
    const int tid  = threadIdx.x;
    const int lane = tid & 63;
    const int wid  = tid >> 6;
    const int quad = lane >> 4;
    const int l16  = lane & 15;

    __shared__ __align__(16) bf16_t xT[64][CC + 8];   // [t_local][c]

    {
        const bf16_t* xb = x + (size_t)b * CC * TT;
        const int tq = tid & 7;
        const int cp = tid >> 3;        // 0..31
        #pragma unroll
        for (int pass = 0; pass < 6; ++pass) {
            const int c = (pass * 32 + cp) * 2;
            U8 r0, r1;
            r0.u = *(const uint4*)(xb + (size_t)c * TT + t0 + tq * 8);
            r1.u = *(const uint4*)(xb + (size_t)(c + 1) * TT + t0 + tq * 8);
            #pragma unroll
            for (int j = 0; j < 8; ++j) {
                U2 p; p.h[0] = r0.h[j]; p.h[1] = r1.h[j];
                *(unsigned int*)&xT[tq * 8 + j][c] = p.u;
            }
        }
    }
    __syncthreads();

    const bf16_t* W = (og < 2) ? Wq : (og < 4) ? Wk : Wv;
    const int obase = (og & 1) * 192 + wid * 48;   // o within [0,384)

    f32x4 acc[4][3];
    const f32x4 zero = {0.f, 0.f, 0.f, 0.f};
    #pragma unroll
    for (int mi = 0; mi < 4; ++mi)
        #pragma unroll
        for (int ni = 0; ni < 3; ++ni) acc[mi][ni] = zero;

    for (int k0 = 0; k0 < CC; k0 += 32) {
        bf16x8 bfr[3];
        #pragma unroll
        for (int ni = 0; ni < 3; ++ni) {
            const int o = obase + ni * 16 + l16;
            bfr[ni] = *(const bf16x8*)(W + (size_t)o * CC + k0 + quad * 8);
        }
        #pragma unroll
        for (int mi = 0; mi < 4; ++mi) {
            bf16x8 afr = *(const bf16x8*)&xT[mi * 16 + l16][k0 + quad * 8];
            #pragma unroll
            for (int ni = 0; ni < 3; ++ni)
                acc[mi][ni] = MFMA16(afr, bfr[ni], acc[mi][ni]);
        }
    }

    #pragma unroll
    for (int mi = 0; mi < 4; ++mi)
        #pragma unroll
        for (int ni = 0; ni < 3; ++ni)
            #pragma unroll
            for (int r = 0; r < 4; ++r) {
                const int tl = mi * 16 + quad * 4 + r;      // D row = t
                const int ol = obase + ni * 16 + l16;       // D col = o
                const bf16_t bv = (bf16_t)acc[mi][ni][r];
                if (og < 2)      qT[((size_t)b * TT + t0 + tl) * CC + ol] = bv;
                else if (og < 4) kT[((size_t)b * TT + t0 + tl) * CC + ol] = bv;
                else             vm[((size_t)b * CC + ol) * TT + t0 + tl] = bv;
            }
}

// ---------------------------------------------------------------------------
// K1b: vrs[b][g][d] = sum_t vm[b][g*64+d][t]
// ---------------------------------------------------------------------------
__global__ __launch_bounds__(256) void vrow_kernel(const bf16_t* __restrict__ vm,
                                                   float* __restrict__ vrs)
{
    const int bg = blockIdx.x;          // b*6+g
    const int d  = threadIdx.x & 63;
    const int qr = threadIdx.x >> 6;
    const bf16_t* row = vm + ((size_t)(bg / 6) * CC + (bg % 6) * 64 + d) * TT + qr * 256;
    float s = 0.f;
    for (int i = 0; i < 256; i += 8) {
        U8 v; v.u = *(const uint4*)(row + i);
        #pragma unroll
        for (int j = 0; j < 8; ++j) s += (float)v.h[j];
    }
    __shared__ float red[4][64];
    red[qr][d] = s;
    __syncthreads();
    if (qr == 0) vrs[bg * 64 + d] = red[0][d] + red[1][d] + red[2][d] + red[3][d];
}

// ---------------------------------------------------------------------------
// K2: fused attention.  Per block: one (b, g, 64-row q-tile).
//   S = (scale*w[g,h] * q)^T k   (K=384 GEMM; head-mix folded into Q)
//   P = exp(S)   (logits ~N(0,1): no max subtraction needed; clamped anyway)
//   l=sum P, l2=sum P^2 per row; U += P @ V^T via LDS round-trip of P
//   emit Uhat = U/l (fp32) + atomicAdd of sum(l2/l^2) (InstanceNorm stat)
// ---------------------------------------------------------------------------
__global__ __launch_bounds__(256) void attn_kernel(
    const bf16_t* __restrict__ qT,
    const bf16_t* __restrict__ kT,
    const bf16_t* __restrict__ vm,
    const bf16_t* __restrict__ head_w,
    float* __restrict__ Uhat,
    float* __restrict__ sumsq)
{
    const int qt = blockIdx.x;
    const int g  = blockIdx.y;
    const int b  = blockIdx.z;
    const int q0 = qt * 64;
    const int tid = threadIdx.x, lane = tid & 63, wid = tid >> 6;
    const int quad = lane >> 4, l16 = lane & 15;

    __shared__ __align__(16) bf16_t qs[64][CC + 8];   // qmix tile, 50 KB
    __shared__ __align__(16) bf16_t Ps[64][72];       // P tile, 9 KB
    __shared__ float  lred[4][64];
    __shared__ float  l2red[4][64];
    __shared__ float  lrow[64];

    float smix[6];
    #pragma unroll
    for (int h = 0; h < 6; ++h) smix[h] = 0.125f * (float)head_w[g * 6 + h];

    // stage qmix: qs[q][hd] = qT[b][q0+q][hd] * smix[hd/64]
    {
        const bf16_t* qb = qT + ((size_t)b * TT + q0) * CC;
        #pragma unroll
        for (int it = 0; it < 12; ++it) {
            const int idx = (it * 256 + tid) * 8;
            const int qr = idx / CC;
            const int cc = idx % CC;              // multiple of 8, head-uniform
            U8 v; v.u = *(const uint4*)(qb + (size_t)qr * CC + cc);
            const float m = smix[cc >> 6];
            U8 o;
            #pragma unroll
            for (int j = 0; j < 8; ++j) o.h[j] = (bf16_t)((float)v.h[j] * m);
            *(uint4*)&qs[qr][cc] = o.u;
        }
    }

    float lacc[4][4] = {{0.f}}, l2acc[4][4] = {{0.f}};
    f32x4 Uacc[4];
    const f32x4 zero = {0.f, 0.f, 0.f, 0.f};
    #pragma unroll
    for (int mi = 0; mi < 4; ++mi) Uacc[mi] = zero;

    const bf16_t* kTb = kT + (size_t)b * TT * CC;
    const bf16_t* vb  = vm + ((size_t)b * CC + g * 64) * TT;

    __syncthreads();

    for (int tt = 0; tt < 16; ++tt) {
        const int t0 = tt * 64;
        // ---- scores: this wave owns t-cols [t0+wid*16, +16) over all 64 q rows
        f32x4 s[4];
        #pragma unroll
        for (int mi = 0; mi < 4; ++mi) s[mi] = zero;
        const bf16_t* kc = kTb + (size_t)(t0 + wid * 16 + l16) * CC + quad * 8;
        for (int k0 = 0; k0 < CC; k0 += 32) {
            bf16x8 bfr = *(const bf16x8*)(kc + k0);
            #pragma unroll
            for (int mi = 0; mi < 4; ++mi) {
                bf16x8 afr = *(const bf16x8*)&qs[mi * 16 + l16][k0 + quad * 8];
                s[mi] = MFMA16(afr, bfr, s[mi]);
            }
        }
        __syncthreads();   // prior iteration's PV reads of Ps are complete
        #pragma unroll
        for (int mi = 0; mi < 4; ++mi)
            #pragma unroll
            for (int r = 0; r < 4; ++r) {
                const float p = __expf(fminf(s[mi][r], 60.0f));
                lacc[mi][r]  += p;
                l2acc[mi][r] += p * p;
                Ps[mi * 16 + quad * 4 + r][wid * 16 + l16] = (bf16_t)p;
            }
        __syncthreads();
        // ---- PV: this wave owns d-cols [wid*16, +16); K = this 64-t tile
        #pragma unroll
        for (int kk = 0; kk < 2; ++kk) {
            bf16x8 bfr = *(const bf16x8*)(vb + (size_t)(wid * 16 + l16) * TT
                                          + t0 + kk * 32 + quad * 8);
            #pragma unroll
            for (int mi = 0; mi < 4; ++mi) {
                bf16x8 afr = *(const bf16x8*)&Ps[mi * 16 + l16][kk * 32 + quad * 8];
                Uacc[mi] = MFMA16(afr, bfr, Uacc[mi]);
            }
        }
    }

    // ---- row stats (lane partials: one t-col per (mi,r) per tile)
    #pragma unroll
    for (int mi = 0; mi < 4; ++mi)
        #pragma unroll
        for (int r = 0; r < 4; ++r) {
            float l = lacc[mi][r], l2 = l2acc[mi][r];
            #pragma unroll
            for (int off = 1; off < 16; off <<= 1) {
                l  += __shfl_xor(l,  off, 64);
                l2 += __shfl_xor(l2, off, 64);
            }
            if (l16 == 0) {
                lred[wid][mi * 16 + quad * 4 + r]  = l;
                l2red[wid][mi * 16 + quad * 4 + r] = l2;
            }
        }
    __syncthreads();
    if (tid < 64) {
        const float l  = lred[0][tid] + lred[1][tid] + lred[2][tid] + lred[3][tid];
        const float l2 = l2red[0][tid] + l2red[1][tid] + l2red[2][tid] + l2red[3][tid];
        lrow[tid] = l;
        float c = l2 / (l * l);          // sum_t attn^2 for this row
        #pragma unroll
        for (int off = 1; off < 64; off <<= 1) c += __shfl_xor(c, off, 64);
        if (tid == 0) atomicAdd(&sumsq[b * 6 + g], c);
    }
    __syncthreads();

    // ---- store Uhat = U / l  (fp32, [B][6][T][64] flat == torch .view order)
    float* Ub = Uhat + (((size_t)b * NHH + g) * TT + q0) * 64;
    #pragma unroll
    for (int mi = 0; mi < 4; ++mi)
        #pragma unroll
        for (int r = 0; r < 4; ++r) {
            const int ql = mi * 16 + quad * 4 + r;
            Ub[(size_t)ql * 64 + wid * 16 + l16] = Uacc[mi][r] / lrow[ql];
        }
}

// ---------------------------------------------------------------------------
// K3: projection + fused InstanceNorm affine + bias + final transpose.
//   Z[t'][c'] = a[h]*Uhat_flat[off] + c[h]*vrs[h][d],  off=t'*384+c', h=off>>16, d=off&63
//   out[b][o][t'] = projb[o] + sum_c Z[t'][c] * projW[o][c]     (FLOAT32 output)
// ---------------------------------------------------------------------------
__global__ __launch_bounds__(256) void proj_kernel(
    const float* __restrict__ Uhat,
    const float* __restrict__ vrs,
    const float* __restrict__ sumsq,
    const bf16_t* __restrict__ gamma,
    const bf16_t* __restrict__ beta,
    const bf16_t* __restrict__ projW,
    const bf16_t* __restrict__ projb,
    float* __restrict__ out)
{
    const int ts = blockIdx.x;
    const int b  = blockIdx.y;
    const int t0 = ts * 32;
    const int tid = threadIdx.x, lane = tid & 63, wid = tid >> 6;
    const int quad = lane >> 4, l16 = lane & 15;

    __shared__ float Ac[6], Cc[6], pb[CC];
    if (tid < 6) {
        const float ss  = sumsq[b * NHH + tid];
        const float var = fmaxf(ss - 1.0f, 0.0f) * (1.0f / 1048576.0f);  // mean=1/T exactly
        const float a   = (float)gamma[tid] * rsqrtf(var + 1e-5f);
        Ac[tid] = a;
        Cc[tid] = (float)beta[tid] - a * (1.0f / 1024.0f);
    }
    for (int i = tid; i < CC; i += 256) pb[i] = (float)projb[i];
    __syncthreads();

    f32x4 acc[6][2];
    const f32x4 zero = {0.f, 0.f, 0.f, 0.f};
    #pragma unroll
    for (int mi = 0; mi < 6; ++mi)
        #pragma unroll
        for (int ni = 0; ni < 2; ++ni) acc[mi][ni] = zero;

    const float* Ub = Uhat + (size_t)b * TT * CC;
    for (int k0 = 0; k0 < CC; k0 += 32) {
        bf16x8 bfr[2];
        #pragma unroll
        for (int ni = 0; ni < 2; ++ni) {
            const int tl = t0 + ni * 16 + l16;
            const int baseoff = tl * CC + k0 + quad * 8;
            f32x4 u0 = *(const f32x4*)(Ub + baseoff);
            f32x4 u1 = *(const f32x4*)(Ub + baseoff + 4);
            U8 z;
            #pragma unroll
            for (int j = 0; j < 8; ++j) {
                const int off = baseoff + j;
                const int h = off >> 16;
                const int d = off & 63;
                const float uv = (j < 4) ? u0[j] : u1[j - 4];
                z.h[j] = (bf16_t)(Ac[h] * uv + Cc[h] * vrs[(b * NHH + h) * 64 + d]);
            }
            bfr[ni] = *(const bf16x8*)&z;
        }
        #pragma unroll
        for (int mi = 0; mi < 6; ++mi) {
            const int o = wid * 96 + mi * 16 + l16;
            bf16x8 afr = *(const bf16x8*)(projW + (size_t)o * CC + k0 + quad * 8);
            #pragma unroll
            for (int ni = 0; ni < 2; ++ni)
                acc[mi][ni] = MFMA16(afr, bfr[ni], acc[mi][ni]);
        }
    }

    #pragma unroll
    for (int mi = 0; mi < 6; ++mi)
        #pragma unroll
        for (int ni = 0; ni < 2; ++ni)
            #pragma unroll
            for (int r = 0; r < 4; ++r) {
                const int o  = wid * 96 + mi * 16 + quad * 4 + r;
                const int tl = t0 + ni * 16 + l16;
                out[((size_t)b * CC + o) * TT + tl] = acc[mi][ni][r] + pb[o];
            }
}

// ---------------------------------------------------------------------------
extern "C" void kernel_launch(void* const* d_in, const int* in_sizes, int n_in,
                              void* d_out, int out_size, void* d_ws, size_t ws_size,
                              hipStream_t stream)
{
    float* outp = (float*)d_out;      // reference output dtype is float32
    char* ws = (char*)d_ws;

    // bump allocator (256B aligned)
    size_t off = 0;
    auto alloc = [&](size_t bytes) {
        void* p = ws + off;
        off += (bytes + 255) & ~(size_t)255;
        return p;
    };

    const size_t szQ = (size_t)BB * TT * CC * sizeof(bf16_t);   // 6 MB

    bf16_t* cx  = (bf16_t*)alloc(szQ);
    bf16_t* cWq = (bf16_t*)alloc((size_t)CC * CC * 2);
    bf16_t* cWk = (bf16_t*)alloc((size_t)CC * CC * 2);
    bf16_t* cWv = (bf16_t*)alloc((size_t)CC * CC * 2);
    bf16_t* cPW = (bf16_t*)alloc((size_t)CC * CC * 2);
    bf16_t* chw = (bf16_t*)alloc(64 * 2);
    bf16_t* cg  = (bf16_t*)alloc(64 * 2);
    bf16_t* cb  = (bf16_t*)alloc(64 * 2);
    bf16_t* cpb = (bf16_t*)alloc(CC * 2);
    bf16_t* qT  = (bf16_t*)alloc(szQ);
    bf16_t* kT  = (bf16_t*)alloc(szQ);
    bf16_t* vm  = (bf16_t*)alloc(szQ);
    float*  Uh  = (float*)alloc((size_t)BB * TT * CC * 4);      // 12 MB
    float*  vr  = (float*)alloc(48 * 64 * 4);
    float*  sq  = (float*)alloc(48 * 4);

    CastArgs ca;
    bf16_t* dsts[9] = {cx, cWq, cWk, cWv, chw, cg, cb, cPW, cpb};
    for (int i = 0; i < 9; ++i) {
        ca.src[i] = d_in[i];
        ca.dst[i] = dsts[i];
        ca.n[i]   = in_sizes[i];
    }

    hipMemsetAsync(sq, 0, 48 * sizeof(float), stream);
    cast_kernel<<<dim3(192, 9), 256, 0, stream>>>(ca);
    qkv_kernel<<<dim3(6, 16, 8), 256, 0, stream>>>(cx, cWq, cWk, cWv, qT, kT, vm);
    vrow_kernel<<<48, 256, 0, stream>>>(vm, vr);
    attn_kernel<<<dim3(16, 6, 8), 256, 0, stream>>>(qT, kT, vm, chw, Uh, sq);
    proj_kernel<<<dim3(32, 8), 256, 0, stream>>>(Uh, vr, sq, cg, cb, cPW, cpb, outp);
}